// Round 6
// baseline (208.542 us; speedup 1.0000x reference)
//
#include <hip/hip_runtime.h>

#define TWO_PI_F 6.283185307179586f
#define EPS_F 1e-6f
#define LOG2E_F 1.4426950408889634f
#define BATCH 32

// Replace non-finite by 0 (bit test so fast-math can't fold it away).
__device__ __forceinline__ float sane(float x) {
    return ((__float_as_uint(x) & 0x7f800000u) == 0x7f800000u) ? 0.f : x;
}

// Broadcast lane l's value to all lanes via v_readlane (SGPR result; VALU-class,
// stays off the LDS pipe — the whole point of the eval-loop restructure).
__device__ __forceinline__ float rlane(float v, int l) {
    return __int_as_float(__builtin_amdgcn_readlane(__float_as_int(v), l));
}

// One fused layer: [apply prev batchnorm] -> gm_convolve -> eval_at_centers ->
// relu_fit (top-KOUT via stable rank) -> write selected comps + abs-integral.
//
// Thread layout: NT = TPG*G threads; t -> (g = t/TPG, kt = t%TPG).
// Active thread (kt < KUSE = NCOMP/KP) owns KP k-slots {kt + j*KUSE} in
// registers; group g sums the n-slice [g*CHUNK, ...).
// Eval inner loop: per 64-n chunk, lane L cooperatively loads n=nb+L's packed
// data (b128+b64, conflict-free), then v_readlane broadcasts each n to SGPRs.
// LDS-pipe traffic: 2 insts per wave per 64 n's (was 2 per n). Quadform coeffs
// are pre-scaled by log2e so the exponential is a bare v_exp_f32 (exp2f).
template<int LO, int LI, int ND, int NK, int NCOMP, int KOUT,
         int KP, int TPG, int G, bool FIRST>
__global__ __launch_bounds__(TPG*G) void layer_kernel(
    const float* __restrict__ in_x,            // FIRST: (B,1,64,7) f32
    const float* __restrict__ prev_sel,        // !FIRST: (B,LI,ND,7) f32
    const float* __restrict__ prev_tot,        // !FIRST: (B,LI) f32
    const float* __restrict__ kern,            // (LO,LI,NK,7) f32
    const float* __restrict__ bias,            // (LO,) f32
    float* __restrict__ out_sel,               // (B,LO,KOUT,7) f32
    float* __restrict__ out_tot)               // (B,LO) f32
{
    constexpr int KUSE   = NCOMP / KP;
    static_assert(KUSE * KP == NCOMP, "exact k tiling required");
    constexpr int CHUNK  = (NCOMP + G - 1) / G;
    constexpr int NCOMP4 = (NCOMP + 3) & ~3;
    constexpr int NQ     = NCOMP4 / 4;
    constexpr int CQ     = (NQ + G - 1) / G;

    const int b    = blockIdx.x / LO;
    const int lo   = blockIdx.x % LO;
    const int tid  = threadIdx.x;
    const int g    = tid / TPG;
    const int kt   = tid % TPG;
    const int lane = tid & 63;
    const bool active = (kt < KUSE);

    __shared__ float  d_w[LI*ND], d_px[LI*ND], d_py[LI*ND];
    __shared__ float4 d_c[LI*ND];
    __shared__ float  k_w[LI*NK], k_px[LI*NK], k_py[LI*NK];
    __shared__ float4 k_c[LI*NK];
    __shared__ float4 eA[NCOMP];   // w, px, py, -0.5*log2e*i00
    __shared__ float2 eB[NCOMP];   // -0.5*log2e*(i01+i10), -0.5*log2e*i11
    __shared__ float4 cC[NCOMP];   // C00,C01,C10,C11
    __shared__ float  w2s[NCOMP];
    __shared__ __align__(16) float a2s[NCOMP4];
    __shared__ float  accbuf[G*TPG*KP];   // eval partials, then rank partials
    __shared__ float  scr[64];
    __shared__ float  selint[32];
    __shared__ float  dscale[LI];

    // ---- Phase pre: incoming batchnorm + stage data/kernel into LDS
    if constexpr (FIRST) {
        // per_gaussian=True batchnorm on raw input (LI==1, ND==64)
        if (tid < ND) {
            const float* s = in_x + (size_t)(b*ND + tid)*7;
            const float w  = sane(s[0]);
            const float c0 = sane(s[3]), c1 = sane(s[4]), c2 = sane(s[5]), c3 = sane(s[6]);
            d_w[tid] = w; d_px[tid] = sane(s[1]); d_py[tid] = sane(s[2]);
            d_c[tid] = make_float4(c0, c1, c2, c3);
            const float det = c0*c3 - c1*c2;
            scr[tid] = sane(fabsf(w) * TWO_PI_F * sqrtf(fmaxf(det, EPS_F)));
        }
        __syncthreads();
        if (tid == 0) {
            float s = 0.f;
            for (int i = 0; i < ND; ++i) s += scr[i];
            dscale[0] = 1.f / (s + EPS_F);
        }
        __syncthreads();
        if (tid < ND) d_w[tid] = sane(d_w[tid] * dscale[0]);
    } else {
        // per_gaussian=False batchnorm: per input channel li, mean over batch
        if (tid < LI) {
            float s = 0.f;
            for (int bb = 0; bb < BATCH; ++bb) s += prev_tot[bb*LI + tid];
            dscale[tid] = 1.f / (s / (float)BATCH + EPS_F);
        }
        __syncthreads();
        if (tid < LI*ND) {
            const int li = tid / ND;
            const float* s = prev_sel + (size_t)(b*LI*ND + tid)*7;
            d_w[tid]  = sane(s[0] * dscale[li]);
            d_px[tid] = s[1]; d_py[tid] = s[2];
            d_c[tid]  = make_float4(s[3], s[4], s[5], s[6]);
        }
    }
    if (tid < LI*NK) {
        const float* s = kern + (size_t)(lo*LI*NK + tid)*7;
        k_w[tid]  = sane(s[0]);
        k_px[tid] = sane(s[1]); k_py[tid] = sane(s[2]);
        k_c[tid]  = make_float4(sane(s[3]), sane(s[4]), sane(s[5]), sane(s[6]));
    }
    __syncthreads();

    // ---- Phase A: gm_convolve -> NCOMP components in LDS
    // Flattening matches reference reshape: (li, nd, nk), nk fastest.
    if (tid < NCOMP) {
        const int li = tid / (ND*NK);
        const int r  = tid % (ND*NK);
        const int nd = r / NK, nk = r % NK;
        const int di = li*ND + nd, ki = li*NK + nk;
        const float4 dc = d_c[di], kc = k_c[ki];
        const float c0 = dc.x + kc.x, c1 = dc.y + kc.y, c2 = dc.z + kc.z, c3 = dc.w + kc.w;
        const float dd = dc.x*dc.w - dc.y*dc.z;
        const float dk = kc.x*kc.w - kc.y*kc.z;
        const float ds = c0*c3 - c1*c2;
        const float w  = sane(d_w[di]*k_w[ki]*TWO_PI_F*sqrtf(fmaxf(dd*dk, 0.f) / fmaxf(ds, EPS_F)));
        const float px = sane(d_px[di] + k_px[ki]);
        const float py = sane(d_py[di] + k_py[ki]);
        const float inv = -0.5f * LOG2E_F / ds;   // fold -1/2 and log2e into inv2
        const float A = sane(c3*inv), Bc = sane(-(c1 + c2)*inv), Cc = sane(c0*inv);
        eA[tid] = make_float4(w, px, py, A);
        eB[tid] = make_float2(Bc, Cc);
        cC[tid] = make_float4(sane(c0), sane(c1), sane(c2), sane(c3));
    }
    __syncthreads();

    // ---- Phase B: eval_at_centers, KP k-slots per thread, n split across G.
    float kx[KP], ky[KP], acc[KP];
    #pragma unroll
    for (int j = 0; j < KP; ++j) {
        acc[j] = 0.f; kx[j] = 0.f; ky[j] = 0.f;
        if (active) { const float4 a = eA[kt + j*KUSE]; kx[j] = a.y; ky[j] = a.z; }
    }
    {
        const int n0 = g*CHUNK;
        const int n1 = (n0 + CHUNK < NCOMP) ? (n0 + CHUNK) : NCOMP;
        for (int nb = n0; nb < n1; nb += 64) {
            const int cnt = (n1 - nb < 64) ? (n1 - nb) : 64;
            int nl = nb + lane; if (nl > NCOMP - 1) nl = NCOMP - 1;  // clamp, unused lanes
            const float4 Pa = eA[nl];   // cooperative: lane L holds n = nb+L
            const float2 Pe = eB[nl];
            #pragma unroll 4
            for (int t = 0; t < cnt; ++t) {
                const float wn  = rlane(Pa.x, t);
                const float pxn = rlane(Pa.y, t);
                const float pyn = rlane(Pa.z, t);
                const float An  = rlane(Pa.w, t);
                const float Bn  = rlane(Pe.x, t);
                const float Cn  = rlane(Pe.y, t);
                #pragma unroll
                for (int j = 0; j < KP; ++j) {
                    const float dx = kx[j] - pxn;
                    const float dy = ky[j] - pyn;
                    const float u  = An*dx + Bn*dy;
                    const float md = dx*u + (Cn*dy)*dy;   // = -0.5*log2e*quadform <= 0
                    acc[j] += wn * exp2f(md);
                }
            }
        }
    }
    if (g > 0 && active) {
        #pragma unroll
        for (int j = 0; j < KP; ++j) accbuf[(g*TPG + kt)*KP + j] = acc[j];
    }
    __syncthreads();

    const float bi = bias[lo];
    if (g == 0 && active) {
        #pragma unroll
        for (int j = 0; j < KP; ++j) {
            float s = acc[j];
            for (int gg = 1; gg < G; ++gg) s += accbuf[(gg*TPG + kt)*KP + j];
            const float v  = s + bi;
            const float sc = fmaxf(v, 0.f) / (fabsf(v) + EPS_F);
            const int   k  = kt + j*KUSE;
            const float ww = sane(eA[k].x * sc);
            w2s[k] = ww;
            a2s[k] = fabsf(ww);
        }
    }
    if constexpr (NCOMP4 > NCOMP) {
        if (tid >= NCOMP && tid < NCOMP4) a2s[tid] = -1.f;  // pad: never ranks
    }
    __syncthreads();

    // ---- Phase C: stable-descending rank (== jax.lax.top_k order), group-split
    // rank(k) = #{j : a2s[j] > a2s[k]  or  (a2s[j] == a2s[k] and j < k)}
    int rank[KP];
    float myv[KP];
    #pragma unroll
    for (int j = 0; j < KP; ++j) rank[j] = 0;
    if (active) {
        #pragma unroll
        for (int j = 0; j < KP; ++j) myv[j] = a2s[kt + j*KUSE];
        const int q0 = g*CQ;
        const int q1 = (q0 + CQ < NQ) ? (q0 + CQ) : NQ;
        for (int q = q0; q < q1; ++q) {
            const float4 v4 = ((const float4*)a2s)[q];  // broadcast
            #pragma unroll
            for (int c = 0; c < 4; ++c) {
                const float vj = (c == 0) ? v4.x : (c == 1) ? v4.y : (c == 2) ? v4.z : v4.w;
                const int   jj = 4*q + c;
                #pragma unroll
                for (int j = 0; j < KP; ++j) {
                    const int myk = kt + j*KUSE;
                    rank[j] += (vj > myv[j] || (vj == myv[j] && jj < myk)) ? 1 : 0;
                }
            }
        }
        if (g > 0) {
            #pragma unroll
            for (int j = 0; j < KP; ++j) accbuf[(g*TPG + kt)*KP + j] = (float)rank[j];
        }
    }
    __syncthreads();

    // ---- Phase D: g==0 finalizes ranks, writes selected comps + integrals
    if (g == 0 && active) {
        #pragma unroll
        for (int j = 0; j < KP; ++j) {
            int r = rank[j];
            for (int gg = 1; gg < G; ++gg) r += (int)accbuf[(gg*TPG + kt)*KP + j];
            if (r < KOUT) {
                const int k = kt + j*KUSE;
                const float4 a = eA[k];
                const float4 c = cC[k];
                const float ww = w2s[k];
                float* dst = out_sel + (size_t)((b*LO + lo)*KOUT + r)*7;
                dst[0] = ww; dst[1] = a.y; dst[2] = a.z;
                dst[3] = c.x; dst[4] = c.y; dst[5] = c.z; dst[6] = c.w;
                const float det = c.x*c.w - c.y*c.z;
                selint[r] = sane(fabsf(ww) * TWO_PI_F * sqrtf(fmaxf(det, EPS_F)));
            }
        }
    }
    __syncthreads();
    if (tid == 0) {
        float s = 0.f;
        for (int i = 0; i < KOUT; ++i) s += selint[i];
        out_tot[b*LO + lo] = s;
    }
}

// Final: batchnorm3 scale (mean over batch) -> integrate -> log_softmax -> f32
__global__ __launch_bounds__(64) void final_kernel(
    const float* __restrict__ sel3,   // (B,10,5,7)
    const float* __restrict__ tot3,   // (B,10)
    float* __restrict__ out)          // (B,10) f32
{
    const int b = blockIdx.x;
    const int tid = threadIdx.x;
    __shared__ float scale3[10], integ[10], red2[2];
    if (tid < 10) {
        float s = 0.f;
        for (int bb = 0; bb < BATCH; ++bb) s += tot3[bb*10 + tid];
        scale3[tid] = 1.f / (s / (float)BATCH + EPS_F);
    }
    __syncthreads();
    if (tid < 10) {
        float s = 0.f;
        const float* base = sel3 + (size_t)((b*10 + tid)*5)*7;
        for (int kk = 0; kk < 5; ++kk) {
            const float* c = base + kk*7;
            const float det = c[3]*c[6] - c[4]*c[5];
            s += c[0] * scale3[tid] * TWO_PI_F * sqrtf(fmaxf(det, EPS_F));
        }
        integ[tid] = sane(s);
    }
    __syncthreads();
    if (tid == 0) {
        float m = -1e30f;
        for (int l = 0; l < 10; ++l) m = fmaxf(m, integ[l]);
        float ss = 0.f;
        for (int l = 0; l < 10; ++l) ss += __expf(integ[l] - m);
        red2[0] = m; red2[1] = logf(ss);
    }
    __syncthreads();
    if (tid < 10) out[b*10 + tid] = integ[tid] - red2[0] - red2[1];
}

extern "C" void kernel_launch(void* const* d_in, const int* in_sizes, int n_in,
                              void* d_out, int out_size, void* d_ws, size_t ws_size,
                              hipStream_t stream)
{
    const float* in_x = (const float*)d_in[0];
    const float* k1   = (const float*)d_in[1];
    const float* k2   = (const float*)d_in[2];
    const float* k3   = (const float*)d_in[3];
    const float* b1   = (const float*)d_in[4];
    const float* b2   = (const float*)d_in[5];
    const float* b3   = (const float*)d_in[6];
    float* out = (float*)d_out;   // reference output dtype is float32

    float* ws = (float*)d_ws;
    float* sel1 = ws;                  // 32*5*25*7  = 28000 floats
    float* tot1 = ws + 28000;          // 160
    float* sel2 = ws + 28160;          // 32*6*12*7  = 16128
    float* tot2 = ws + 44288;          // 192
    float* sel3 = ws + 44480;          // 32*10*5*7  = 11200
    float* tot3 = ws + 55680;          // 320  (total ~224 KB)

    // Layer 1: 320 comps, keep 25.  KP=5 (64*5=320), TPG=64, G=16 -> NT=1024.
    layer_kernel<5, 1, 64, 5, 320, 25, 5, 64, 16, true><<<BATCH*5, 1024, 0, stream>>>(
        in_x, nullptr, nullptr, k1, b1, sel1, tot1);
    // Layer 2: 625 comps, keep 12.  KP=5 (125*5=625), TPG=128, G=8 -> NT=1024.
    layer_kernel<6, 5, 25, 5, 625, 12, 5, 128, 8, false><<<BATCH*6, 1024, 0, stream>>>(
        nullptr, sel1, tot1, k2, b2, sel2, tot2);
    // Layer 3: 360 comps, keep 5.   KP=6 (60*6=360), TPG=64, G=6 -> NT=384.
    layer_kernel<10, 6, 12, 5, 360, 5, 6, 64, 6, false><<<BATCH*10, 384, 0, stream>>>(
        nullptr, sel2, tot2, k3, b3, sel3, tot3);
    // Final: batchnorm + integrate + log_softmax
    final_kernel<<<BATCH, 64, 0, stream>>>(sel3, tot3, out);
}

// Round 7
// 170.439 us; speedup vs baseline: 1.2236x; 1.2236x over previous
//
#include <hip/hip_runtime.h>

#define TWO_PI_F 6.283185307179586f
#define EPS_F 1e-6f
#define LOG2E_F 1.4426950408889634f
#define BATCH 32

// Replace non-finite by 0 (bit test so fast-math can't fold it away).
__device__ __forceinline__ float sane(float x) {
    return ((__float_as_uint(x) & 0x7f800000u) == 0x7f800000u) ? 0.f : x;
}

// One fused layer: [apply prev batchnorm] -> gm_convolve -> eval_at_centers ->
// relu_fit (top-KOUT via stable rank) -> write selected comps + abs-integral.
//
// Thread layout: NT = TPG*G threads; t -> (g = t/TPG, kt = t%TPG).
// Active thread (kt < KUSE = NCOMP/KP) owns KP k-slots {kt + j*KUSE} in
// registers; group g sums the n-slice [g*CHUNK, ...).
//
// Eval uses POLYNOMIAL form: md = a*kx^2 + b*kx*ky + c*ky^2 + d*kx + e*ky + f
// with (-0.5*log2e) folded into a..f at conv time, and per-k (kx,ky,kx2,ky2,
// kxy) cached in registers -> 5 FMA + exp2 + acc-FMA = 7 VALU per cell (was
// 10). Per-n data arrives as two uniform-address ds_read_b128 broadcasts,
// which run on the LDS pipe and overlap with VALU (round-6 lesson: do NOT
// move this onto the VALU port via readlane).
template<int LO, int LI, int ND, int NK, int NCOMP, int KOUT,
         int KP, int TPG, int G, bool FIRST>
__global__ __launch_bounds__(TPG*G) void layer_kernel(
    const float* __restrict__ in_x,            // FIRST: (B,1,64,7) f32
    const float* __restrict__ prev_sel,        // !FIRST: (B,LI,ND,7) f32
    const float* __restrict__ prev_tot,        // !FIRST: (B,LI) f32
    const float* __restrict__ kern,            // (LO,LI,NK,7) f32
    const float* __restrict__ bias,            // (LO,) f32
    float* __restrict__ out_sel,               // (B,LO,KOUT,7) f32
    float* __restrict__ out_tot)               // (B,LO) f32
{
    constexpr int KUSE   = NCOMP / KP;
    static_assert(KUSE * KP == NCOMP, "exact k tiling required");
    constexpr int CHUNK  = (NCOMP + G - 1) / G;
    constexpr int NCOMP4 = (NCOMP + 3) & ~3;
    constexpr int NQ     = NCOMP4 / 4;
    constexpr int CQ     = (NQ + G - 1) / G;

    const int b   = blockIdx.x / LO;
    const int lo  = blockIdx.x % LO;
    const int tid = threadIdx.x;
    const int g   = tid / TPG;
    const int kt  = tid % TPG;
    const bool active = (kt < KUSE);

    // Staging arrays (dead after Phase A) union'd with accbuf (live Phase B+).
    struct StageT {
        float4 d_c[LI*ND];
        float4 k_c[LI*NK];
        float  d_w[LI*ND], d_px[LI*ND], d_py[LI*ND];
        float  k_w[LI*NK], k_px[LI*NK], k_py[LI*NK];
    };
    constexpr size_t ACCB = (size_t)(G > 1 ? (G-1)*TPG*KP : 1) * sizeof(float);
    constexpr size_t UB   = sizeof(StageT) > ACCB ? sizeof(StageT) : ACCB;
    __shared__ __align__(16) unsigned char u_smem[UB];
    StageT& st    = *reinterpret_cast<StageT*>(u_smem);
    float* accbuf = reinterpret_cast<float*>(u_smem);

    __shared__ float2 cPos[NCOMP];  // px, py
    __shared__ float4 nP[NCOMP];    // a, b, c, d   (log2e-folded quadform)
    __shared__ float4 nQ[NCOMP];    // e, f, w, 0
    __shared__ float4 cC[NCOMP];    // C00,C01,C10,C11
    __shared__ float  w2s[NCOMP];
    __shared__ __align__(16) float a2s[NCOMP4];
    __shared__ float  scr[64];
    __shared__ float  selint[32];
    __shared__ float  dscale[LI];

    // ---- Phase pre: incoming batchnorm + stage data/kernel into LDS
    if constexpr (FIRST) {
        // per_gaussian=True batchnorm on raw input (LI==1, ND==64)
        if (tid < ND) {
            const float* s = in_x + (size_t)(b*ND + tid)*7;
            const float w  = sane(s[0]);
            const float c0 = sane(s[3]), c1 = sane(s[4]), c2 = sane(s[5]), c3 = sane(s[6]);
            st.d_w[tid] = w; st.d_px[tid] = sane(s[1]); st.d_py[tid] = sane(s[2]);
            st.d_c[tid] = make_float4(c0, c1, c2, c3);
            const float det = c0*c3 - c1*c2;
            scr[tid] = sane(fabsf(w) * TWO_PI_F * sqrtf(fmaxf(det, EPS_F)));
        }
        __syncthreads();
        if (tid == 0) {
            float s = 0.f;
            for (int i = 0; i < ND; ++i) s += scr[i];
            dscale[0] = 1.f / (s + EPS_F);
        }
        __syncthreads();
        if (tid < ND) st.d_w[tid] = sane(st.d_w[tid] * dscale[0]);
    } else {
        // per_gaussian=False batchnorm: per input channel li, mean over batch
        if (tid < LI) {
            float s = 0.f;
            for (int bb = 0; bb < BATCH; ++bb) s += prev_tot[bb*LI + tid];
            dscale[tid] = 1.f / (s / (float)BATCH + EPS_F);
        }
        __syncthreads();
        if (tid < LI*ND) {
            const int li = tid / ND;
            const float* s = prev_sel + (size_t)(b*LI*ND + tid)*7;
            st.d_w[tid]  = sane(s[0] * dscale[li]);
            st.d_px[tid] = s[1]; st.d_py[tid] = s[2];
            st.d_c[tid]  = make_float4(s[3], s[4], s[5], s[6]);
        }
    }
    if (tid < LI*NK) {
        const float* s = kern + (size_t)(lo*LI*NK + tid)*7;
        st.k_w[tid]  = sane(s[0]);
        st.k_px[tid] = sane(s[1]); st.k_py[tid] = sane(s[2]);
        st.k_c[tid]  = make_float4(sane(s[3]), sane(s[4]), sane(s[5]), sane(s[6]));
    }
    __syncthreads();

    // ---- Phase A: gm_convolve -> NCOMP components in LDS (poly coefficients)
    // Flattening matches reference reshape: (li, nd, nk), nk fastest.
    if (tid < NCOMP) {
        const int li = tid / (ND*NK);
        const int r  = tid % (ND*NK);
        const int nd = r / NK, nk = r % NK;
        const int di = li*ND + nd, ki = li*NK + nk;
        const float4 dc = st.d_c[di], kc = st.k_c[ki];
        const float c0 = dc.x + kc.x, c1 = dc.y + kc.y, c2 = dc.z + kc.z, c3 = dc.w + kc.w;
        const float dd = dc.x*dc.w - dc.y*dc.z;
        const float dk = kc.x*kc.w - kc.y*kc.z;
        const float ds = c0*c3 - c1*c2;
        const float w  = sane(st.d_w[di]*st.k_w[ki]*TWO_PI_F*sqrtf(fmaxf(dd*dk, 0.f) / fmaxf(ds, EPS_F)));
        const float px = sane(st.d_px[di] + st.k_px[ki]);
        const float py = sane(st.d_py[di] + st.k_py[ki]);
        const float inv = -0.5f * LOG2E_F / ds;      // fold -1/2 and log2e
        const float a  = sane(c3*inv);
        const float bb = sane(-(c1 + c2)*inv);
        const float cc = sane(c0*inv);
        const float dd2 = sane(-(2.f*a*px + bb*py));
        const float ee  = sane(-(2.f*cc*py + bb*px));
        const float ff  = sane((a*px + bb*py)*px + cc*py*py);
        cPos[tid] = make_float2(px, py);
        nP[tid]   = make_float4(a, bb, cc, dd2);
        nQ[tid]   = make_float4(ee, ff, w, 0.f);
        cC[tid]   = make_float4(sane(c0), sane(c1), sane(c2), sane(c3));
    }
    __syncthreads();

    // ---- Phase B: eval_at_centers, KP k-slots per thread, n split across G
    float kx[KP], ky[KP], kx2[KP], ky2[KP], kxy[KP], acc[KP];
    #pragma unroll
    for (int j = 0; j < KP; ++j) {
        acc[j] = 0.f; kx[j] = 0.f; ky[j] = 0.f;
        if (active) { const float2 p = cPos[kt + j*KUSE]; kx[j] = p.x; ky[j] = p.y; }
        kx2[j] = kx[j]*kx[j]; ky2[j] = ky[j]*ky[j]; kxy[j] = kx[j]*ky[j];
    }
    {
        const int n0 = g*CHUNK;
        const int n1 = (n0 + CHUNK < NCOMP) ? (n0 + CHUNK) : NCOMP;
        #pragma unroll 2
        for (int n = n0; n < n1; ++n) {
            const float4 P = nP[n];   // uniform-address broadcast (LDS pipe)
            const float4 Q = nQ[n];
            #pragma unroll
            for (int j = 0; j < KP; ++j) {
                const float md = fmaf(P.x, kx2[j],
                                 fmaf(P.y, kxy[j],
                                 fmaf(P.z, ky2[j],
                                 fmaf(P.w, kx[j],
                                 fmaf(Q.x, ky[j], Q.y)))));
                acc[j] = fmaf(Q.z, exp2f(md), acc[j]);
            }
        }
    }
    if (g > 0 && active) {
        #pragma unroll
        for (int j = 0; j < KP; ++j) accbuf[((g-1)*TPG + kt)*KP + j] = acc[j];
    }
    __syncthreads();

    const float bi = bias[lo];
    if (g == 0 && active) {
        #pragma unroll
        for (int j = 0; j < KP; ++j) {
            float s = acc[j];
            for (int gg = 1; gg < G; ++gg) s += accbuf[((gg-1)*TPG + kt)*KP + j];
            const float v  = s + bi;
            const float sc = fmaxf(v, 0.f) / (fabsf(v) + EPS_F);
            const int   k  = kt + j*KUSE;
            const float ww = sane(nQ[k].z * sc);
            w2s[k] = ww;
            a2s[k] = fabsf(ww);
        }
    }
    if constexpr (NCOMP4 > NCOMP) {
        if (tid >= NCOMP && tid < NCOMP4) a2s[tid] = -1.f;  // pad: never ranks
    }
    __syncthreads();

    // ---- Phase C: stable-descending rank (== jax.lax.top_k order), group-split
    // rank(k) = #{j : a2s[j] > a2s[k]  or  (a2s[j] == a2s[k] and j < k)}
    int rank[KP];
    float myv[KP];
    #pragma unroll
    for (int j = 0; j < KP; ++j) rank[j] = 0;
    if (active) {
        #pragma unroll
        for (int j = 0; j < KP; ++j) myv[j] = a2s[kt + j*KUSE];
        const int q0 = g*CQ;
        const int q1 = (q0 + CQ < NQ) ? (q0 + CQ) : NQ;
        for (int q = q0; q < q1; ++q) {
            const float4 v4 = ((const float4*)a2s)[q];  // broadcast
            #pragma unroll
            for (int c = 0; c < 4; ++c) {
                const float vj = (c == 0) ? v4.x : (c == 1) ? v4.y : (c == 2) ? v4.z : v4.w;
                const int   jj = 4*q + c;
                #pragma unroll
                for (int j = 0; j < KP; ++j) {
                    const int myk = kt + j*KUSE;
                    rank[j] += (vj > myv[j] || (vj == myv[j] && jj < myk)) ? 1 : 0;
                }
            }
        }
        if (g > 0) {
            #pragma unroll
            for (int j = 0; j < KP; ++j) accbuf[((g-1)*TPG + kt)*KP + j] = (float)rank[j];
        }
    }
    __syncthreads();

    // ---- Phase D: g==0 finalizes ranks, writes selected comps + integrals
    if (g == 0 && active) {
        #pragma unroll
        for (int j = 0; j < KP; ++j) {
            int r = rank[j];
            for (int gg = 1; gg < G; ++gg) r += (int)accbuf[((gg-1)*TPG + kt)*KP + j];
            if (r < KOUT) {
                const int k = kt + j*KUSE;
                const float2 p = cPos[k];
                const float4 c = cC[k];
                const float ww = w2s[k];
                float* dst = out_sel + (size_t)((b*LO + lo)*KOUT + r)*7;
                dst[0] = ww; dst[1] = p.x; dst[2] = p.y;
                dst[3] = c.x; dst[4] = c.y; dst[5] = c.z; dst[6] = c.w;
                const float det = c.x*c.w - c.y*c.z;
                selint[r] = sane(fabsf(ww) * TWO_PI_F * sqrtf(fmaxf(det, EPS_F)));
            }
        }
    }
    __syncthreads();
    if (tid == 0) {
        float s = 0.f;
        for (int i = 0; i < KOUT; ++i) s += selint[i];
        out_tot[b*LO + lo] = s;
    }
}

// Final: batchnorm3 scale (mean over batch) -> integrate -> log_softmax -> f32
__global__ __launch_bounds__(64) void final_kernel(
    const float* __restrict__ sel3,   // (B,10,5,7)
    const float* __restrict__ tot3,   // (B,10)
    float* __restrict__ out)          // (B,10) f32
{
    const int b = blockIdx.x;
    const int tid = threadIdx.x;
    __shared__ float scale3[10], integ[10], red2[2];
    if (tid < 10) {
        float s = 0.f;
        for (int bb = 0; bb < BATCH; ++bb) s += tot3[bb*10 + tid];
        scale3[tid] = 1.f / (s / (float)BATCH + EPS_F);
    }
    __syncthreads();
    if (tid < 10) {
        float s = 0.f;
        const float* base = sel3 + (size_t)((b*10 + tid)*5)*7;
        for (int kk = 0; kk < 5; ++kk) {
            const float* c = base + kk*7;
            const float det = c[3]*c[6] - c[4]*c[5];
            s += c[0] * scale3[tid] * TWO_PI_F * sqrtf(fmaxf(det, EPS_F));
        }
        integ[tid] = sane(s);
    }
    __syncthreads();
    if (tid == 0) {
        float m = -1e30f;
        for (int l = 0; l < 10; ++l) m = fmaxf(m, integ[l]);
        float ss = 0.f;
        for (int l = 0; l < 10; ++l) ss += __expf(integ[l] - m);
        red2[0] = m; red2[1] = logf(ss);
    }
    __syncthreads();
    if (tid < 10) out[b*10 + tid] = integ[tid] - red2[0] - red2[1];
}

extern "C" void kernel_launch(void* const* d_in, const int* in_sizes, int n_in,
                              void* d_out, int out_size, void* d_ws, size_t ws_size,
                              hipStream_t stream)
{
    const float* in_x = (const float*)d_in[0];
    const float* k1   = (const float*)d_in[1];
    const float* k2   = (const float*)d_in[2];
    const float* k3   = (const float*)d_in[3];
    const float* b1   = (const float*)d_in[4];
    const float* b2   = (const float*)d_in[5];
    const float* b3   = (const float*)d_in[6];
    float* out = (float*)d_out;   // reference output dtype is float32

    float* ws = (float*)d_ws;
    float* sel1 = ws;                  // 32*5*25*7  = 28000 floats
    float* tot1 = ws + 28000;          // 160
    float* sel2 = ws + 28160;          // 32*6*12*7  = 16128
    float* tot2 = ws + 44288;          // 192
    float* sel3 = ws + 44480;          // 32*10*5*7  = 11200
    float* tot3 = ws + 55680;          // 320  (total ~224 KB)

    // Layer 1: 320 comps, keep 25.  KP=5 (64*5=320), TPG=64, G=16 -> NT=1024.
    layer_kernel<5, 1, 64, 5, 320, 25, 5, 64, 16, true><<<BATCH*5, 1024, 0, stream>>>(
        in_x, nullptr, nullptr, k1, b1, sel1, tot1);
    // Layer 2: 625 comps, keep 12.  KP=5 (125*5=625), TPG=128, G=8 -> NT=1024.
    layer_kernel<6, 5, 25, 5, 625, 12, 5, 128, 8, false><<<BATCH*6, 1024, 0, stream>>>(
        nullptr, sel1, tot1, k2, b2, sel2, tot2);
    // Layer 3: 360 comps, keep 5.   KP=6 (60*6=360), TPG=64, G=12 -> NT=768.
    layer_kernel<10, 6, 12, 5, 360, 5, 6, 64, 12, false><<<BATCH*10, 768, 0, stream>>>(
        nullptr, sel2, tot2, k3, b3, sel3, tot3);
    // Final: batchnorm + integrate + log_softmax
    final_kernel<<<BATCH, 64, 0, stream>>>(sel3, tot3, out);
}